// Round 1
// baseline (9877.110 us; speedup 1.0000x reference)
//
#include <hip/hip_runtime.h>
#include <hip/hip_bf16.h>
#include <cstddef>

#define BB 64
#define TT 1024
#define HH 512
#define II 64
#define OO 8
#define NOISE_STD 0.05f
#define ALPHA 0.2f

// ---------------- precompute effective weights into workspace ----------------
__global__ void precomp_kernel(const float* __restrict__ wrec,
                               const float* __restrict__ wrec_mask,
                               const float* __restrict__ wi,
                               const float* __restrict__ wi_mask,
                               float* __restrict__ ws_wrec,
                               float* __restrict__ ws_wi) {
    int idx = blockIdx.x * 256 + threadIdx.x;
    if (idx < HH * HH) {
        ws_wrec[idx] = fabsf(wrec[idx]) * wrec_mask[idx];
    } else {
        int r = idx - HH * HH;   // r < II*HH by grid sizing
        ws_wi[r] = wi[r] * wi_mask[r];
    }
}

// ---------------- recurrent kernel: one block per batch element ----------------
template <bool RAW>
__global__ __launch_bounds__(512)
void rnn_rec(const float* __restrict__ input, const float* __restrict__ noise,
             const float* __restrict__ wi, const float* __restrict__ si,
             const float* __restrict__ wrec, const float* __restrict__ bvec,
             const float* __restrict__ wo, const float* __restrict__ so,
             const float* __restrict__ wi_mask, const float* __restrict__ wrec_mask,
             const float* __restrict__ wo_mask, const float* __restrict__ h0,
             const float* __restrict__ ws_wrec, const float* __restrict__ ws_wi,
             float* __restrict__ out, float* __restrict__ traj) {
    const int bb = blockIdx.x;
    const int tid = threadIdx.x;
    const int j = tid;                 // column owned by this thread

    __shared__ float r_sh[2][HH];      // relu(h), double-buffered
    __shared__ float x_sh[2][II];      // x_t * si, double-buffered
    __shared__ float wo_sh[OO][HH];    // wo * so * wo_mask (transposed)

    // per-thread constants / state
    float h  = h0[j];
    float ab = ALPHA * bvec[j];

    // wo_sh[o][j] = wo[j][o] * so[o] * wo_mask[j][o]
    #pragma unroll
    for (int o = 0; o < OO; ++o) {
        wo_sh[o][tid] = wo[tid * OO + o] * so[o] * wo_mask[tid * OO + o];
    }

    const float* inp    = input + (size_t)bb * TT * II;
    const float* noisep = noise + (size_t)bb * TT * HH;
    float* outp  = out  + (size_t)bb * TT * OO;
    float* trajp = traj + (size_t)bb * (TT + 1) * HH;

    float sreg = (tid < II) ? si[tid] : 0.f;
    if (tid < II) x_sh[0][tid] = inp[tid] * sreg;
    r_sh[0][j] = fmaxf(h, 0.f);
    trajp[j] = h;                       // trajectories[:,0,:] = h0
    float ncur = noisep[j];
    __syncthreads();

    const int w = tid >> 6;             // wave id == output index
    const int l = tid & 63;             // lane

    for (int t = 0; t < TT; ++t) {
        const int cur = t & 1, nxt = cur ^ 1;

        // prefetch next-step x and noise (safe: buffers last read before prev sync)
        const int tn = (t + 1 < TT) ? (t + 1) : t;
        if (tid < II) x_sh[nxt][tid] = inp[tn * II + tid] * sreg;
        float nnext = noisep[(size_t)tn * HH + j];

        // ---- r @ wrec_eff (column j), 4 accumulators ----
        float a0 = 0.f, a1 = 0.f, a2 = 0.f, a3 = 0.f;
        if (!RAW) {
            const float* wc = ws_wrec + j;
            #pragma unroll 4
            for (int k = 0; k < HH; k += 4) {
                float r0 = r_sh[cur][k], r1 = r_sh[cur][k + 1];
                float r2 = r_sh[cur][k + 2], r3 = r_sh[cur][k + 3];
                a0 = fmaf(r0, wc[(k)     * HH], a0);
                a1 = fmaf(r1, wc[(k + 1) * HH], a1);
                a2 = fmaf(r2, wc[(k + 2) * HH], a2);
                a3 = fmaf(r3, wc[(k + 3) * HH], a3);
            }
        } else {
            const float* wc = wrec + j;
            const float* mc = wrec_mask + j;
            #pragma unroll 4
            for (int k = 0; k < HH; k += 4) {
                a0 = fmaf(r_sh[cur][k],     fabsf(wc[(k)     * HH]) * mc[(k)     * HH], a0);
                a1 = fmaf(r_sh[cur][k + 1], fabsf(wc[(k + 1) * HH]) * mc[(k + 1) * HH], a1);
                a2 = fmaf(r_sh[cur][k + 2], fabsf(wc[(k + 2) * HH]) * mc[(k + 2) * HH], a2);
                a3 = fmaf(r_sh[cur][k + 3], fabsf(wc[(k + 3) * HH]) * mc[(k + 3) * HH], a3);
            }
        }

        // ---- (x*si) @ (wi*mask) (column j) ----
        float accx = 0.f;
        if (!RAW) {
            const float* wic = ws_wi + j;
            #pragma unroll 8
            for (int k = 0; k < II; ++k) accx = fmaf(x_sh[cur][k], wic[k * HH], accx);
        } else {
            const float* wic = wi + j;
            const float* mic = wi_mask + j;
            #pragma unroll 8
            for (int k = 0; k < II; ++k)
                accx = fmaf(x_sh[cur][k], wic[k * HH] * mic[k * HH], accx);
        }

        // ---- state update ----
        float hn = (1.f - ALPHA) * h + NOISE_STD * ncur
                 + ALPHA * ((a0 + a1) + (a2 + a3) + accx) + ab;
        h = hn;
        trajp[(size_t)(t + 1) * HH + j] = h;
        float rh = fmaxf(h, 0.f);
        r_sh[nxt][j] = rh;
        ncur = nnext;
        __syncthreads();

        // ---- output projection: wave w computes out[b,t,w] ----
        float p = 0.f;
        #pragma unroll
        for (int m = 0; m < 8; ++m)
            p = fmaf(r_sh[nxt][l + 64 * m], wo_sh[w][l + 64 * m], p);
        #pragma unroll
        for (int d = 32; d >= 1; d >>= 1) p += __shfl_xor(p, d, 64);
        if (l == 0) outp[t * OO + w] = p;
    }
}

// ---------------- host launcher ----------------
extern "C" void kernel_launch(void* const* d_in, const int* in_sizes, int n_in,
                              void* d_out, int out_size, void* d_ws, size_t ws_size,
                              hipStream_t stream) {
    const float* input     = (const float*)d_in[0];
    const float* noise     = (const float*)d_in[1];
    const float* wi        = (const float*)d_in[2];
    const float* si        = (const float*)d_in[3];
    const float* wrec      = (const float*)d_in[4];
    const float* bvec      = (const float*)d_in[5];
    const float* wo        = (const float*)d_in[6];
    const float* so        = (const float*)d_in[7];
    const float* wi_mask   = (const float*)d_in[8];
    const float* wrec_mask = (const float*)d_in[9];
    const float* wo_mask   = (const float*)d_in[10];
    const float* h0        = (const float*)d_in[11];

    float* out  = (float*)d_out;
    float* traj = out + (size_t)BB * TT * OO;

    const size_t need = (size_t)(HH * HH + II * HH) * sizeof(float);
    if (ws_size >= need) {
        float* ws_wrec = (float*)d_ws;
        float* ws_wi   = ws_wrec + HH * HH;
        precomp_kernel<<<(HH * HH + II * HH) / 256, 256, 0, stream>>>(
            wrec, wrec_mask, wi, wi_mask, ws_wrec, ws_wi);
        rnn_rec<false><<<BB, 512, 0, stream>>>(
            input, noise, wi, si, wrec, bvec, wo, so,
            wi_mask, wrec_mask, wo_mask, h0, ws_wrec, ws_wi, out, traj);
    } else {
        rnn_rec<true><<<BB, 512, 0, stream>>>(
            input, noise, wi, si, wrec, bvec, wo, so,
            wi_mask, wrec_mask, wo_mask, h0, nullptr, nullptr, out, traj);
    }
}

// Round 3
// 7018.087 us; speedup vs baseline: 1.4074x; 1.4074x over previous
//
#include <hip/hip_runtime.h>
#include <hip/hip_bf16.h>
#include <cstddef>
#include <cstdint>

#define BB 64
#define TT 1024
#define HH 512
#define II 64
#define OO 8
#define NOISE_STD 0.05f
#define ALPHA 0.2f

#define G_SLICES 16      // blocks (column slices) per clique
#define BT 4             // batches per clique
#define NC (BB/BT)       // 16 cliques
#define K2EXT 320        // 640 extended-K / 2 (f16 pairs): 512 wrec + 64 wi + 1 bias + pad
#define K4EXT 160
#define R2STRIDE 328     // r2 row stride in half2 slots (mult of 4 for b128)

typedef _Float16 half2_t __attribute__((ext_vector_type(2)));

#if __has_builtin(__builtin_amdgcn_fdot2)
__device__ __forceinline__ float fdot2f(half2_t a, half2_t b, float c) {
    return __builtin_amdgcn_fdot2(a, b, c, false);
}
#else
__device__ __forceinline__ float fdot2f(half2_t a, half2_t b, float c) {
    return c + (float)a[0] * (float)b[0] + (float)a[1] * (float)b[1];
}
#endif

__device__ __forceinline__ half2_t pkrtz(float a, float b) {
    return __builtin_bit_cast(half2_t, __builtin_amdgcn_cvt_pkrtz(a, b));
}

__global__ __launch_bounds__(512, 2)
void rnn_clique(const float* __restrict__ input, const float* __restrict__ noise,
                const float* __restrict__ wi, const float* __restrict__ si,
                const float* __restrict__ wrec, const float* __restrict__ bvec,
                const float* __restrict__ wo, const float* __restrict__ so,
                const float* __restrict__ wi_mask, const float* __restrict__ wrec_mask,
                const float* __restrict__ wo_mask, const float* __restrict__ h0,
                unsigned* __restrict__ flags, float* __restrict__ out,
                float* __restrict__ traj)
{
    const int tid  = threadIdx.x;
    const int cq   = blockIdx.x >> 4;   // clique = batch group
    const int sl   = blockIdx.x & 15;   // column slice
    const int wv   = tid >> 6;
    const int lane = tid & 63;

    __shared__ half2_t w2[K4EXT * 64];       // [k4][c][j], 40 KB
    __shared__ half2_t r2[BT][R2STRIDE];     // extended activation pairs
    __shared__ float   part[BT][8][32];      // per-wave matvec partials
    __shared__ half2_t wo2[256];             // wo_eff column (sl<8)

    // ---------------- stage extended weight slice (one-time) ----------------
    {
        const int c = tid & 31, kg = tid >> 5;   // kg 0..15
        const int gc = sl * 32 + c;
        for (int m = 0; m < 10; ++m) {
            int k4 = m * 16 + kg;
            float v[4];
            #pragma unroll
            for (int q = 0; q < 4; ++q) {
                int kap = k4 * 4 + q;
                float x;
                if (kap < HH) {
                    x = fabsf(wrec[(size_t)kap * HH + gc]) * wrec_mask[(size_t)kap * HH + gc];
                } else if (kap < HH + II) {
                    int i = kap - HH;
                    x = wi[(size_t)i * HH + gc] * si[i] * wi_mask[(size_t)i * HH + gc];
                } else if (kap == HH + II) {
                    x = bvec[gc];
                } else {
                    x = 0.f;
                }
                v[q] = x;
            }
            w2[k4 * 64 + c * 2]     = pkrtz(v[0], v[1]);
            w2[k4 * 64 + c * 2 + 1] = pkrtz(v[2], v[3]);
        }
    }
    if (sl < OO && tid < 256) {      // wo column for this block's output index
        int k2 = tid, o = sl;
        float v0 = wo[(size_t)(2 * k2) * OO + o] * so[o] * wo_mask[(size_t)(2 * k2) * OO + o];
        float v1 = wo[(size_t)(2 * k2 + 1) * OO + o] * so[o] * wo_mask[(size_t)(2 * k2 + 1) * OO + o];
        wo2[k2] = pkrtz(v0, v1);
    }
    if (tid < 128) {                 // r2 slots 0..255 from relu(h0)
        int k4 = tid;
        float v0 = fmaxf(h0[4 * k4 + 0], 0.f), v1 = fmaxf(h0[4 * k4 + 1], 0.f);
        float v2 = fmaxf(h0[4 * k4 + 2], 0.f), v3 = fmaxf(h0[4 * k4 + 3], 0.f);
        half2_t p0 = pkrtz(v0, v1), p1 = pkrtz(v2, v3);
        for (int b = 0; b < BT; ++b) { r2[b][2 * k4] = p0; r2[b][2 * k4 + 1] = p1; }
    }
    if (tid < BT) {                  // const slot (bias) + zero pads
        r2[tid][288] = half2_t{(_Float16)1.f, (_Float16)0.f};
        for (int s = 289; s < R2STRIDE; ++s) r2[tid][s] = half2_t{(_Float16)0.f, (_Float16)0.f};
    }
    if (wv >= 4 && lane < 32) {      // x[t=0] slots 256..287
        int b = wv - 4, i2 = lane;
        const float* xp = input + ((size_t)(cq * BT + b) * TT + 0) * II + 2 * i2;
        r2[b][256 + i2] = pkrtz(xp[0], xp[1]);
    }

    // persistent per-lane state for finalize lanes (waves 0..3, lanes 0..31)
    float h_st = 0.f, n_reg = 0.f;
    float* trajp = nullptr;
    const float* noisep = nullptr;
    if (wv < BT && lane < 32) {
        int b = wv, c = lane, gc = sl * 32 + c, bg = cq * BT + b;
        h_st   = h0[gc];
        noisep = noise + (size_t)bg * TT * HH;
        trajp  = traj + (size_t)bg * (TT + 1) * HH;
        n_reg  = noisep[gc];       // noise[b][0][gc]
        trajp[gc] = h_st;          // trajectories[:,0,:]
    }
    __syncthreads();

    const int c_    = lane & 31;
    const int shalf = lane >> 5;
    const int seg   = wv * 2 + shalf;          // 0..15, k2 range [seg*20, seg*20+20)
    unsigned* myflag = flags + cq * 16 + sl;

    for (int t = 0; t < TT; ++t) {
        // ---- ph1: matvec over extended K (wrec + wi + bias folded) ----
        float acc0 = 0.f, acc1 = 0.f, acc2 = 0.f, acc3 = 0.f;
        #pragma unroll
        for (int ch = 0; ch < 5; ++ch) {
            int k2b = seg * 20 + ch * 4;
            int k4b = seg * 10 + ch * 2;
            half2_t w00 = w2[k4b * 64 + c_ * 2];
            half2_t w01 = w2[k4b * 64 + c_ * 2 + 1];
            half2_t w10 = w2[(k4b + 1) * 64 + c_ * 2];
            half2_t w11 = w2[(k4b + 1) * 64 + c_ * 2 + 1];
            {
                half2_t ra = r2[0][k2b], rb = r2[0][k2b + 1], rc = r2[0][k2b + 2], rd = r2[0][k2b + 3];
                acc0 = fdot2f(ra, w00, acc0); acc0 = fdot2f(rb, w01, acc0);
                acc0 = fdot2f(rc, w10, acc0); acc0 = fdot2f(rd, w11, acc0);
            }
            {
                half2_t ra = r2[1][k2b], rb = r2[1][k2b + 1], rc = r2[1][k2b + 2], rd = r2[1][k2b + 3];
                acc1 = fdot2f(ra, w00, acc1); acc1 = fdot2f(rb, w01, acc1);
                acc1 = fdot2f(rc, w10, acc1); acc1 = fdot2f(rd, w11, acc1);
            }
            {
                half2_t ra = r2[2][k2b], rb = r2[2][k2b + 1], rc = r2[2][k2b + 2], rd = r2[2][k2b + 3];
                acc2 = fdot2f(ra, w00, acc2); acc2 = fdot2f(rb, w01, acc2);
                acc2 = fdot2f(rc, w10, acc2); acc2 = fdot2f(rd, w11, acc2);
            }
            {
                half2_t ra = r2[3][k2b], rb = r2[3][k2b + 1], rc = r2[3][k2b + 2], rd = r2[3][k2b + 3];
                acc3 = fdot2f(ra, w00, acc3); acc3 = fdot2f(rb, w01, acc3);
                acc3 = fdot2f(rc, w10, acc3); acc3 = fdot2f(rd, w11, acc3);
            }
        }
        // pre-reduce across the wave's two k-halves
        acc0 += __shfl_xor(acc0, 32);
        acc1 += __shfl_xor(acc1, 32);
        acc2 += __shfl_xor(acc2, 32);
        acc3 += __shfl_xor(acc3, 32);
        if (shalf == 0) {
            part[0][wv][c_] = acc0;
            part[1][wv][c_] = acc1;
            part[2][wv][c_] = acc2;
            part[3][wv][c_] = acc3;
        }
        __syncthreads();   // ph2

        // ---- ph3: finalize h_new (waves 0-3) | deferred out-proj (waves 4-7) ----
        if (wv < BT && lane < 32) {
            int b = wv, c = lane, gc = sl * 32 + c;
            float mv = 0.f;
            #pragma unroll
            for (int m = 0; m < 8; ++m) mv += part[b][m][c];
            float hn = (1.f - ALPHA) * h_st + ALPHA * mv + NOISE_STD * n_reg;
            h_st = hn;
            __hip_atomic_store(trajp + (size_t)(t + 1) * HH + gc, hn,
                               __ATOMIC_RELAXED, __HIP_MEMORY_SCOPE_AGENT);
            int tn = (t + 1 < TT) ? (t + 1) : (TT - 1);
            n_reg = noisep[(size_t)tn * HH + gc];
        } else if (wv >= 4 && sl < OO && t > 0) {
            int b = wv - 4;
            int k2 = lane * 4;
            float p = 0.f;
            p = fdot2f(r2[b][k2],     wo2[k2],     p);
            p = fdot2f(r2[b][k2 + 1], wo2[k2 + 1], p);
            p = fdot2f(r2[b][k2 + 2], wo2[k2 + 2], p);
            p = fdot2f(r2[b][k2 + 3], wo2[k2 + 3], p);
            #pragma unroll
            for (int d = 32; d >= 1; d >>= 1) p += __shfl_xor(p, d);
            if (lane == 0) out[((size_t)(cq * BT + b) * TT + (t - 1)) * OO + sl] = p;
        }
        __syncthreads();   // ph4 (drains traj stores: barrier implies vmcnt(0))

        // ---- ph5: flag + poll ----
        if (wv == 0) {
            if (lane == 0)
                __hip_atomic_store(myflag, (unsigned)(t + 1),
                                   __ATOMIC_RELEASE, __HIP_MEMORY_SCOPE_AGENT);
            const unsigned tgt = (unsigned)(t + 1);
            for (;;) {
                unsigned v = __hip_atomic_load(flags + cq * 16 + (lane & 15),
                                               __ATOMIC_RELAXED, __HIP_MEMORY_SCOPE_AGENT);
                if (__ballot(v >= tgt) == ~0ull) break;
                __builtin_amdgcn_s_sleep(1);
            }
        }
        __syncthreads();   // ph6

        // ---- ph7: gather full state -> r2 (cache-bypassing atomic loads) ----
        {
            int b = tid >> 7, k4 = tid & 127;
            const float* src = traj + ((size_t)(cq * BT + b) * (TT + 1) + (t + 1)) * HH + 4 * k4;
            float v0 = __hip_atomic_load(src + 0, __ATOMIC_RELAXED, __HIP_MEMORY_SCOPE_AGENT);
            float v1 = __hip_atomic_load(src + 1, __ATOMIC_RELAXED, __HIP_MEMORY_SCOPE_AGENT);
            float v2 = __hip_atomic_load(src + 2, __ATOMIC_RELAXED, __HIP_MEMORY_SCOPE_AGENT);
            float v3 = __hip_atomic_load(src + 3, __ATOMIC_RELAXED, __HIP_MEMORY_SCOPE_AGENT);
            v0 = fmaxf(v0, 0.f); v1 = fmaxf(v1, 0.f);
            v2 = fmaxf(v2, 0.f); v3 = fmaxf(v3, 0.f);
            r2[b][2 * k4]     = pkrtz(v0, v1);
            r2[b][2 * k4 + 1] = pkrtz(v2, v3);
        }
        if (wv >= 4 && lane < 32) {   // stage x[t+1] into slots 256..287
            int b = wv - 4, i2 = lane;
            int tn = (t + 1 < TT) ? (t + 1) : (TT - 1);
            const float* xp = input + ((size_t)(cq * BT + b) * TT + tn) * II + 2 * i2;
            r2[b][256 + i2] = pkrtz(xp[0], xp[1]);
        }
        __syncthreads();   // ph8
    }

    // ---- epilogue: out[:, TT-1, :] from r2 = relu(h_TT) ----
    if (wv >= 4 && sl < OO) {
        int b = wv - 4;
        int k2 = lane * 4;
        float p = 0.f;
        p = fdot2f(r2[b][k2],     wo2[k2],     p);
        p = fdot2f(r2[b][k2 + 1], wo2[k2 + 1], p);
        p = fdot2f(r2[b][k2 + 2], wo2[k2 + 2], p);
        p = fdot2f(r2[b][k2 + 3], wo2[k2 + 3], p);
        #pragma unroll
        for (int d = 32; d >= 1; d >>= 1) p += __shfl_xor(p, d);
        if (lane == 0) out[((size_t)(cq * BT + b) * TT + (TT - 1)) * OO + sl] = p;
    }
}

// ---------------- host launcher ----------------
extern "C" void kernel_launch(void* const* d_in, const int* in_sizes, int n_in,
                              void* d_out, int out_size, void* d_ws, size_t ws_size,
                              hipStream_t stream) {
    const float* input     = (const float*)d_in[0];
    const float* noise     = (const float*)d_in[1];
    const float* wi        = (const float*)d_in[2];
    const float* si        = (const float*)d_in[3];
    const float* wrec      = (const float*)d_in[4];
    const float* bvec      = (const float*)d_in[5];
    const float* wo        = (const float*)d_in[6];
    const float* so        = (const float*)d_in[7];
    const float* wi_mask   = (const float*)d_in[8];
    const float* wrec_mask = (const float*)d_in[9];
    const float* wo_mask   = (const float*)d_in[10];
    const float* h0        = (const float*)d_in[11];

    float* out  = (float*)d_out;
    float* traj = out + (size_t)BB * TT * OO;
    unsigned* flags = (unsigned*)d_ws;

    // reset clique flags every call (replay-safe)
    (void)hipMemsetAsync(d_ws, 0, NC * G_SLICES * sizeof(unsigned), stream);

    rnn_clique<<<dim3(NC * G_SLICES), dim3(512), 0, stream>>>(
        input, noise, wi, si, wrec, bvec, wo, so,
        wi_mask, wrec_mask, wo_mask, h0, flags, out, traj);
}

// Round 4
// 6498.060 us; speedup vs baseline: 1.5200x; 1.0800x over previous
//
#include <hip/hip_runtime.h>
#include <hip/hip_bf16.h>
#include <cstddef>
#include <cstdint>

#define BB 64
#define TT 1024
#define HH 512
#define II 64
#define OO 8
#define NOISE_STD 0.05f
#define ALPHA 0.2f

#define G_SLICES 16      // blocks (column slices) per clique
#define BT 4             // batches per clique
#define NC (BB/BT)       // 16 cliques
#define K4EXT 160
#define R2STRIDE 328     // r2 row stride in half2 slots

typedef _Float16 half2_t __attribute__((ext_vector_type(2)));
typedef float float4_t __attribute__((ext_vector_type(4)));

#if __has_builtin(__builtin_amdgcn_fdot2)
__device__ __forceinline__ float fdot2f(half2_t a, half2_t b, float c) {
    return __builtin_amdgcn_fdot2(a, b, c, false);
}
#else
__device__ __forceinline__ float fdot2f(half2_t a, half2_t b, float c) {
    return c + (float)a[0] * (float)b[0] + (float)a[1] * (float)b[1];
}
#endif

__device__ __forceinline__ half2_t pkrtz(float a, float b) {
    return __builtin_bit_cast(half2_t, __builtin_amdgcn_cvt_pkrtz(a, b));
}

// agent-coherent (sc1) coalesced 16B load: bypasses non-coherent local L2,
// same coherence bit the compiler emits for __hip_atomic_load(AGENT).
__device__ __forceinline__ float4_t load_coh_f4(const float* p) {
    float4_t v;
    asm volatile("global_load_dwordx4 %0, %1, off sc1\n\t"
                 "s_waitcnt vmcnt(0)"
                 : "=v"(v) : "v"(p) : "memory");
    return v;
}

// agent-coherent (sc1) store (write-through to coherence point)
__device__ __forceinline__ void store_coh_f1(float* p, float v) {
    asm volatile("global_store_dword %0, %1, off sc1"
                 :: "v"(p), "v"(v) : "memory");
}

__global__ __launch_bounds__(512, 2)
void rnn_clique(const float* __restrict__ input, const float* __restrict__ noise,
                const float* __restrict__ wi, const float* __restrict__ si,
                const float* __restrict__ wrec, const float* __restrict__ bvec,
                const float* __restrict__ wo, const float* __restrict__ so,
                const float* __restrict__ wi_mask, const float* __restrict__ wrec_mask,
                const float* __restrict__ wo_mask, const float* __restrict__ h0,
                unsigned* __restrict__ flags, float* __restrict__ out,
                float* __restrict__ traj)
{
    const int tid  = threadIdx.x;
    const int cq   = blockIdx.x >> 4;   // clique = batch group
    const int sl   = blockIdx.x & 15;   // column slice
    const int wv   = tid >> 6;
    const int lane = tid & 63;

    __shared__ half2_t w2[K4EXT * 64];       // [k4][c][j], 40 KB
    __shared__ half2_t r2[BT][R2STRIDE];     // extended activation pairs
    __shared__ float   part[BT][8][32];      // per-wave matvec partials
    __shared__ half2_t wo2[256];             // wo_eff column (sl<8)

    // ---------------- stage extended weight slice (one-time) ----------------
    {
        const int c = tid & 31, kg = tid >> 5;   // kg 0..15
        const int gc = sl * 32 + c;
        for (int m = 0; m < 10; ++m) {
            int k4 = m * 16 + kg;
            float v[4];
            #pragma unroll
            for (int q = 0; q < 4; ++q) {
                int kap = k4 * 4 + q;
                float x;
                if (kap < HH) {
                    x = fabsf(wrec[(size_t)kap * HH + gc]) * wrec_mask[(size_t)kap * HH + gc];
                } else if (kap < HH + II) {
                    int i = kap - HH;
                    x = wi[(size_t)i * HH + gc] * si[i] * wi_mask[(size_t)i * HH + gc];
                } else if (kap == HH + II) {
                    x = bvec[gc];
                } else {
                    x = 0.f;
                }
                v[q] = x;
            }
            w2[k4 * 64 + c * 2]     = pkrtz(v[0], v[1]);
            w2[k4 * 64 + c * 2 + 1] = pkrtz(v[2], v[3]);
        }
    }
    if (sl < OO && tid < 256) {      // wo column for this block's output index
        int k2 = tid, o = sl;
        float v0 = wo[(size_t)(2 * k2) * OO + o] * so[o] * wo_mask[(size_t)(2 * k2) * OO + o];
        float v1 = wo[(size_t)(2 * k2 + 1) * OO + o] * so[o] * wo_mask[(size_t)(2 * k2 + 1) * OO + o];
        wo2[k2] = pkrtz(v0, v1);
    }
    if (tid < 128) {                 // r2 slots 0..255 from relu(h0)
        int k4 = tid;
        float v0 = fmaxf(h0[4 * k4 + 0], 0.f), v1 = fmaxf(h0[4 * k4 + 1], 0.f);
        float v2 = fmaxf(h0[4 * k4 + 2], 0.f), v3 = fmaxf(h0[4 * k4 + 3], 0.f);
        half2_t p0 = pkrtz(v0, v1), p1 = pkrtz(v2, v3);
        for (int b = 0; b < BT; ++b) { r2[b][2 * k4] = p0; r2[b][2 * k4 + 1] = p1; }
    }
    if (tid < BT) {                  // const slot (bias) + zero pads
        r2[tid][288] = half2_t{(_Float16)1.f, (_Float16)0.f};
        for (int s = 289; s < R2STRIDE; ++s) r2[tid][s] = half2_t{(_Float16)0.f, (_Float16)0.f};
    }
    if (wv >= 4 && lane < 32) {      // x[t=0] slots 256..287
        int b = wv - 4, i2 = lane;
        const float* xp = input + ((size_t)(cq * BT + b) * TT + 0) * II + 2 * i2;
        r2[b][256 + i2] = pkrtz(xp[0], xp[1]);
    }

    // persistent per-lane state for finalize lanes (waves 0..3, lanes 0..31)
    float h_st = 0.f, n_reg = 0.f;
    float* trajp = nullptr;
    const float* noisep = nullptr;
    if (wv < BT && lane < 32) {
        int b = wv, c = lane, gc = sl * 32 + c, bg = cq * BT + b;
        h_st   = h0[gc];
        noisep = noise + (size_t)bg * TT * HH;
        trajp  = traj + (size_t)bg * (TT + 1) * HH;
        n_reg  = noisep[gc];            // noise[b][0][gc]
        store_coh_f1(trajp + gc, h_st); // trajectories[:,0,:]
    }
    __syncthreads();

    const int c_    = lane & 31;
    const int shalf = lane >> 5;
    const int seg   = wv * 2 + shalf;          // 0..15, k2 range [seg*20, seg*20+20)
    unsigned* myflag = flags + cq * 16 + sl;

    for (int t = 0; t < TT; ++t) {
        // ---- ph1: matvec over extended K (wrec + wi + bias folded) ----
        float acc0 = 0.f, acc1 = 0.f, acc2 = 0.f, acc3 = 0.f;
        #pragma unroll
        for (int ch = 0; ch < 5; ++ch) {
            int k2b = seg * 20 + ch * 4;
            int k4b = seg * 10 + ch * 2;
            half2_t w00 = w2[k4b * 64 + c_ * 2];
            half2_t w01 = w2[k4b * 64 + c_ * 2 + 1];
            half2_t w10 = w2[(k4b + 1) * 64 + c_ * 2];
            half2_t w11 = w2[(k4b + 1) * 64 + c_ * 2 + 1];
            {
                half2_t ra = r2[0][k2b], rb = r2[0][k2b + 1], rc = r2[0][k2b + 2], rd = r2[0][k2b + 3];
                acc0 = fdot2f(ra, w00, acc0); acc0 = fdot2f(rb, w01, acc0);
                acc0 = fdot2f(rc, w10, acc0); acc0 = fdot2f(rd, w11, acc0);
            }
            {
                half2_t ra = r2[1][k2b], rb = r2[1][k2b + 1], rc = r2[1][k2b + 2], rd = r2[1][k2b + 3];
                acc1 = fdot2f(ra, w00, acc1); acc1 = fdot2f(rb, w01, acc1);
                acc1 = fdot2f(rc, w10, acc1); acc1 = fdot2f(rd, w11, acc1);
            }
            {
                half2_t ra = r2[2][k2b], rb = r2[2][k2b + 1], rc = r2[2][k2b + 2], rd = r2[2][k2b + 3];
                acc2 = fdot2f(ra, w00, acc2); acc2 = fdot2f(rb, w01, acc2);
                acc2 = fdot2f(rc, w10, acc2); acc2 = fdot2f(rd, w11, acc2);
            }
            {
                half2_t ra = r2[3][k2b], rb = r2[3][k2b + 1], rc = r2[3][k2b + 2], rd = r2[3][k2b + 3];
                acc3 = fdot2f(ra, w00, acc3); acc3 = fdot2f(rb, w01, acc3);
                acc3 = fdot2f(rc, w10, acc3); acc3 = fdot2f(rd, w11, acc3);
            }
        }
        // pre-reduce across the wave's two k-halves
        acc0 += __shfl_xor(acc0, 32);
        acc1 += __shfl_xor(acc1, 32);
        acc2 += __shfl_xor(acc2, 32);
        acc3 += __shfl_xor(acc3, 32);
        if (shalf == 0) {
            part[0][wv][c_] = acc0;
            part[1][wv][c_] = acc1;
            part[2][wv][c_] = acc2;
            part[3][wv][c_] = acc3;
        }
        __syncthreads();   // ph2

        // ---- ph3: finalize h_new (waves 0-3) | deferred out-proj (waves 4-7) ----
        if (wv < BT && lane < 32) {
            int b = wv, c = lane, gc = sl * 32 + c;
            float mv = 0.f;
            #pragma unroll
            for (int m = 0; m < 8; ++m) mv += part[b][m][c];
            float hn = (1.f - ALPHA) * h_st + ALPHA * mv + NOISE_STD * n_reg;
            h_st = hn;
            store_coh_f1(trajp + (size_t)(t + 1) * HH + gc, hn);
            int tn = (t + 1 < TT) ? (t + 1) : (TT - 1);
            n_reg = noisep[(size_t)tn * HH + gc];
        } else if (wv >= 4 && sl < OO && t > 0) {
            int b = wv - 4;
            int k2 = lane * 4;
            float p = 0.f;
            p = fdot2f(r2[b][k2],     wo2[k2],     p);
            p = fdot2f(r2[b][k2 + 1], wo2[k2 + 1], p);
            p = fdot2f(r2[b][k2 + 2], wo2[k2 + 2], p);
            p = fdot2f(r2[b][k2 + 3], wo2[k2 + 3], p);
            #pragma unroll
            for (int d = 32; d >= 1; d >>= 1) p += __shfl_xor(p, d);
            if (lane == 0) out[((size_t)(cq * BT + b) * TT + (t - 1)) * OO + sl] = p;
        }
        __syncthreads();   // ph4 (barrier drain: all sc1 h-stores complete)

        // ---- ph5: flag + poll ----
        if (wv == 0) {
            if (lane == 0)
                __hip_atomic_store(myflag, (unsigned)(t + 1),
                                   __ATOMIC_RELEASE, __HIP_MEMORY_SCOPE_AGENT);
            const unsigned tgt = (unsigned)(t + 1);
            for (;;) {
                unsigned v = __hip_atomic_load(flags + cq * 16 + (lane & 15),
                                               __ATOMIC_RELAXED, __HIP_MEMORY_SCOPE_AGENT);
                if (__ballot(v >= tgt) == ~0ull) break;
                __builtin_amdgcn_s_sleep(1);
            }
        }
        __syncthreads();   // ph6

        // ---- ph7: gather full state -> r2 (coalesced sc1 16B loads) ----
        {
            int b = tid >> 7, k4g = tid & 127;
            const float* src = traj + ((size_t)(cq * BT + b) * (TT + 1) + (t + 1)) * HH + 4 * k4g;
            float4_t v = load_coh_f4(src);
            float v0 = fmaxf(v[0], 0.f), v1 = fmaxf(v[1], 0.f);
            float v2 = fmaxf(v[2], 0.f), v3 = fmaxf(v[3], 0.f);
            r2[b][2 * k4g]     = pkrtz(v0, v1);
            r2[b][2 * k4g + 1] = pkrtz(v2, v3);
        }
        if (wv >= 4 && lane < 32) {   // stage x[t+1] into slots 256..287
            int b = wv - 4, i2 = lane;
            int tn = (t + 1 < TT) ? (t + 1) : (TT - 1);
            const float* xp = input + ((size_t)(cq * BT + b) * TT + tn) * II + 2 * i2;
            r2[b][256 + i2] = pkrtz(xp[0], xp[1]);
        }
        __syncthreads();   // ph8
    }

    // ---- epilogue: out[:, TT-1, :] from r2 = relu(h_TT) ----
    if (wv >= 4 && sl < OO) {
        int b = wv - 4;
        int k2 = lane * 4;
        float p = 0.f;
        p = fdot2f(r2[b][k2],     wo2[k2],     p);
        p = fdot2f(r2[b][k2 + 1], wo2[k2 + 1], p);
        p = fdot2f(r2[b][k2 + 2], wo2[k2 + 2], p);
        p = fdot2f(r2[b][k2 + 3], wo2[k2 + 3], p);
        #pragma unroll
        for (int d = 32; d >= 1; d >>= 1) p += __shfl_xor(p, d);
        if (lane == 0) out[((size_t)(cq * BT + b) * TT + (TT - 1)) * OO + sl] = p;
    }
}

// ---------------- host launcher ----------------
extern "C" void kernel_launch(void* const* d_in, const int* in_sizes, int n_in,
                              void* d_out, int out_size, void* d_ws, size_t ws_size,
                              hipStream_t stream) {
    const float* input     = (const float*)d_in[0];
    const float* noise     = (const float*)d_in[1];
    const float* wi        = (const float*)d_in[2];
    const float* si        = (const float*)d_in[3];
    const float* wrec      = (const float*)d_in[4];
    const float* bvec      = (const float*)d_in[5];
    const float* wo        = (const float*)d_in[6];
    const float* so        = (const float*)d_in[7];
    const float* wi_mask   = (const float*)d_in[8];
    const float* wrec_mask = (const float*)d_in[9];
    const float* wo_mask   = (const float*)d_in[10];
    const float* h0        = (const float*)d_in[11];

    float* out  = (float*)d_out;
    float* traj = out + (size_t)BB * TT * OO;
    unsigned* flags = (unsigned*)d_ws;

    // reset clique flags every call (replay-safe)
    (void)hipMemsetAsync(d_ws, 0, NC * G_SLICES * sizeof(unsigned), stream);

    rnn_clique<<<dim3(NC * G_SLICES), dim3(512), 0, stream>>>(
        input, noise, wi, si, wrec, bvec, wo, so,
        wi_mask, wrec_mask, wo_mask, h0, flags, out, traj);
}

// Round 7
// 1802.306 us; speedup vs baseline: 5.4803x; 3.6054x over previous
//
#include <hip/hip_runtime.h>
#include <hip/hip_bf16.h>
#include <cstddef>
#include <cstdint>

#define BB 64
#define TT 1024
#define HH 512
#define II 64
#define OO 8
#define NOISE_STD 0.05f
#define ALPHA 0.2f

#define G_SLICES 16      // blocks (column slices) per clique
#define BT 4             // batches per clique
#define NC (BB/BT)       // 16 cliques
#define K4EXT 160
#define R2STRIDE 328     // r2 row stride in half2 slots

typedef _Float16 half2_t __attribute__((ext_vector_type(2)));
typedef unsigned int uint32;
typedef uint32 uint4_t __attribute__((ext_vector_type(4)));

#if __has_builtin(__builtin_amdgcn_fdot2)
__device__ __forceinline__ float fdot2f(half2_t a, half2_t b, float c) {
    return __builtin_amdgcn_fdot2(a, b, c, false);
}
#else
__device__ __forceinline__ float fdot2f(half2_t a, half2_t b, float c) {
    return c + (float)a[0] * (float)b[0] + (float)a[1] * (float)b[1];
}
#endif

__device__ __forceinline__ half2_t pkrtz(float a, float b) {
    return __builtin_bit_cast(half2_t, __builtin_amdgcn_cvt_pkrtz(a, b));
}

// 4 tagged columns (16B) coherent load, bypasses non-coherent local L2
__device__ __forceinline__ uint4_t load4_sc1(const uint32* p) {
    uint4_t v;
    asm volatile("global_load_dwordx4 %0, %1, off sc1\n\t"
                 "s_waitcnt vmcnt(0)"
                 : "=v"(v) : "v"(p) : "memory");
    return v;
}

__global__ __launch_bounds__(512, 2)
void rnn_clique(const float* __restrict__ input, const float* __restrict__ noise,
                const float* __restrict__ wi, const float* __restrict__ si,
                const float* __restrict__ wrec, const float* __restrict__ bvec,
                const float* __restrict__ wo, const float* __restrict__ so,
                const float* __restrict__ wi_mask, const float* __restrict__ wrec_mask,
                const float* __restrict__ wo_mask, const float* __restrict__ h0,
                uint32* __restrict__ ex, float* __restrict__ out,
                float* __restrict__ traj)
{
    const int tid  = threadIdx.x;
    const int cq   = blockIdx.x >> 4;   // clique = batch group
    const int sl   = blockIdx.x & 15;   // column slice
    const int wv   = tid >> 6;
    const int lane = tid & 63;

    __shared__ half2_t w2[K4EXT * 64];       // [k4][c][j], 40 KB
    __shared__ half2_t r2[BT][R2STRIDE];     // extended activation pairs
    __shared__ float   part[BT][8][32];      // per-wave matvec partials
    __shared__ half2_t wo2[256];             // wo_eff column (sl<8)

    // ---------------- stage extended weight slice (one-time) ----------------
    {
        const int c = tid & 31, kg = tid >> 5;   // kg 0..15
        const int gc = sl * 32 + c;
        for (int m = 0; m < 10; ++m) {
            int k4 = m * 16 + kg;
            float v[4];
            #pragma unroll
            for (int q = 0; q < 4; ++q) {
                int kap = k4 * 4 + q;
                float x;
                if (kap < HH) {
                    x = fabsf(wrec[(size_t)kap * HH + gc]) * wrec_mask[(size_t)kap * HH + gc];
                } else if (kap < HH + II) {
                    int i = kap - HH;
                    x = wi[(size_t)i * HH + gc] * si[i] * wi_mask[(size_t)i * HH + gc];
                } else if (kap == HH + II) {
                    x = bvec[gc];
                } else {
                    x = 0.f;
                }
                v[q] = x;
            }
            w2[k4 * 64 + c * 2]     = pkrtz(v[0], v[1]);
            w2[k4 * 64 + c * 2 + 1] = pkrtz(v[2], v[3]);
        }
    }
    if (sl < OO && tid < 256) {      // wo column for this block's output index
        int k2 = tid, o = sl;
        float v0 = wo[(size_t)(2 * k2) * OO + o] * so[o] * wo_mask[(size_t)(2 * k2) * OO + o];
        float v1 = wo[(size_t)(2 * k2 + 1) * OO + o] * so[o] * wo_mask[(size_t)(2 * k2 + 1) * OO + o];
        wo2[k2] = pkrtz(v0, v1);
    }
    if (tid < 128) {                 // r2 slots 0..255 from relu(h0)
        int k4 = tid;
        float v0 = fmaxf(h0[4 * k4 + 0], 0.f), v1 = fmaxf(h0[4 * k4 + 1], 0.f);
        float v2 = fmaxf(h0[4 * k4 + 2], 0.f), v3 = fmaxf(h0[4 * k4 + 3], 0.f);
        half2_t p0 = pkrtz(v0, v1), p1 = pkrtz(v2, v3);
        for (int b = 0; b < BT; ++b) { r2[b][2 * k4] = p0; r2[b][2 * k4 + 1] = p1; }
    }
    if (tid < BT) {                  // const slot + zero pads
        r2[tid][288] = half2_t{(_Float16)1.f, (_Float16)0.f};
        for (int s = 289; s < R2STRIDE; ++s) r2[tid][s] = half2_t{(_Float16)0.f, (_Float16)0.f};
    }
    if (wv >= 4 && lane < 32) {      // x[t=0] slots 256..287
        int b = wv - 4, i2 = lane;
        const float* xp = input + ((size_t)(cq * BT + b) * TT + 0) * II + 2 * i2;
        r2[b][256 + i2] = pkrtz(xp[0], xp[1]);
    }

    // persistent per-lane state for finalize lanes (waves 0..3, lanes 0..31)
    float h_st = 0.f, n_reg = 0.f;
    float* trajp = nullptr;
    const float* noisep = nullptr;
    uint32* exw = nullptr;   // writer's word slot base (parity 0)
    if (wv < BT && lane < 32) {
        int b = wv, c = lane, gc = sl * 32 + c, bg = cq * BT + b;
        h_st   = h0[gc];
        noisep = noise + (size_t)bg * TT * HH;
        trajp  = traj + (size_t)bg * (TT + 1) * HH;
        n_reg  = noisep[gc];            // noise[b][0][gc]
        trajp[gc] = h_st;               // trajectories[:,0,:] (plain store)
        exw = ex + (size_t)((cq * 2 + 0) * BT + b) * HH + gc;
    }
    __syncthreads();

    const int c_    = lane & 31;
    const int shalf = lane >> 5;
    const int seg   = wv * 2 + shalf;          // 0..15, k2 range [seg*20, seg*20+20)

    // gather mapping: thread covers 4 consecutive columns (one dwordx4)
    const int gb  = tid >> 7;          // batch 0..3
    const int k4g = tid & 127;         // column group
    uint32* exg0 = ex + (size_t)((cq * 2 + 0) * BT + gb) * HH + (size_t)(4 * k4g);
    const size_t expar = (size_t)BT * HH;   // parity stride in uints

    for (int t = 0; t < TT; ++t) {
        // ---- ph1: matvec over extended K (wrec + wi + bias folded) ----
        float acc0 = 0.f, acc1 = 0.f, acc2 = 0.f, acc3 = 0.f;
        #pragma unroll
        for (int ch = 0; ch < 5; ++ch) {
            int k2b = seg * 20 + ch * 4;
            int k4b = seg * 10 + ch * 2;
            half2_t w00 = w2[k4b * 64 + c_ * 2];
            half2_t w01 = w2[k4b * 64 + c_ * 2 + 1];
            half2_t w10 = w2[(k4b + 1) * 64 + c_ * 2];
            half2_t w11 = w2[(k4b + 1) * 64 + c_ * 2 + 1];
            {
                half2_t ra = r2[0][k2b], rb = r2[0][k2b + 1], rc = r2[0][k2b + 2], rd = r2[0][k2b + 3];
                acc0 = fdot2f(ra, w00, acc0); acc0 = fdot2f(rb, w01, acc0);
                acc0 = fdot2f(rc, w10, acc0); acc0 = fdot2f(rd, w11, acc0);
            }
            {
                half2_t ra = r2[1][k2b], rb = r2[1][k2b + 1], rc = r2[1][k2b + 2], rd = r2[1][k2b + 3];
                acc1 = fdot2f(ra, w00, acc1); acc1 = fdot2f(rb, w01, acc1);
                acc1 = fdot2f(rc, w10, acc1); acc1 = fdot2f(rd, w11, acc1);
            }
            {
                half2_t ra = r2[2][k2b], rb = r2[2][k2b + 1], rc = r2[2][k2b + 2], rd = r2[2][k2b + 3];
                acc2 = fdot2f(ra, w00, acc2); acc2 = fdot2f(rb, w01, acc2);
                acc2 = fdot2f(rc, w10, acc2); acc2 = fdot2f(rd, w11, acc2);
            }
            {
                half2_t ra = r2[3][k2b], rb = r2[3][k2b + 1], rc = r2[3][k2b + 2], rd = r2[3][k2b + 3];
                acc3 = fdot2f(ra, w00, acc3); acc3 = fdot2f(rb, w01, acc3);
                acc3 = fdot2f(rc, w10, acc3); acc3 = fdot2f(rd, w11, acc3);
            }
        }
        acc0 += __shfl_xor(acc0, 32);
        acc1 += __shfl_xor(acc1, 32);
        acc2 += __shfl_xor(acc2, 32);
        acc3 += __shfl_xor(acc3, 32);
        if (shalf == 0) {
            part[0][wv][c_] = acc0;
            part[1][wv][c_] = acc1;
            part[2][wv][c_] = acc2;
            part[3][wv][c_] = acc3;
        }
        __syncthreads();   // B1

        const uint32 tag = (uint32)(t + 1);
        const size_t poff = (size_t)((t + 1) & 1) * expar;

        // ---- ph3: finalize+publish (waves 0-3) | out-proj + x-stage (waves 4-7) ----
        if (wv < BT && lane < 32) {
            int b = wv, c = lane, gc = sl * 32 + c;
            float mv = 0.f;
            #pragma unroll
            for (int m = 0; m < 8; ++m) mv += part[b][m][c];
            float hn = (1.f - ALPHA) * h_st + ALPHA * mv + NOISE_STD * n_reg;
            h_st = hn;
            // pack f16(relu(h)) | tag<<16 into ONE dword: single-copy atomic,
            // tag-valid => value-valid (no 8B tearing possible)
            uint32 r16 = __builtin_bit_cast(uint32,
                           __builtin_amdgcn_cvt_pkrtz(fmaxf(hn, 0.f), 0.f)) & 0xFFFFu;
            uint32 word = (tag << 16) | r16;
            __hip_atomic_store(exw + poff, word,
                               __ATOMIC_RELAXED, __HIP_MEMORY_SCOPE_AGENT);
            trajp[(size_t)(t + 1) * HH + gc] = hn;                // plain output store
            int tn = (t + 1 < TT) ? (t + 1) : (TT - 1);
            n_reg = noisep[(size_t)tn * HH + gc];
        } else if (wv >= 4) {
            if (sl < OO && t > 0) {
                int b = wv - 4;
                int k2 = lane * 4;
                float p = 0.f;
                p = fdot2f(r2[b][k2],     wo2[k2],     p);
                p = fdot2f(r2[b][k2 + 1], wo2[k2 + 1], p);
                p = fdot2f(r2[b][k2 + 2], wo2[k2 + 2], p);
                p = fdot2f(r2[b][k2 + 3], wo2[k2 + 3], p);
                #pragma unroll
                for (int d = 32; d >= 1; d >>= 1) p += __shfl_xor(p, d);
                if (lane == 0) out[((size_t)(cq * BT + b) * TT + (t - 1)) * OO + sl] = p;
            }
            if (lane < 32) {          // stage x[t+1] into slots 256..287
                int b = wv - 4, i2 = lane;
                int tn = (t + 1 < TT) ? (t + 1) : (TT - 1);
                const float* xp = input + ((size_t)(cq * BT + b) * TT + tn) * II + 2 * i2;
                r2[b][256 + i2] = pkrtz(xp[0], xp[1]);
            }
        }
        __syncthreads();   // B2 (out-proj done reading r2 before gather overwrites)

        // ---- ph7: tagged gather of relu(h_{t+1}) (poll the data itself) ----
        {
            const uint32* g0 = exg0 + poff;
            uint4_t w;
            for (;;) {
                w = load4_sc1(g0);
                if ((w[0] >> 16) == tag && (w[1] >> 16) == tag &&
                    (w[2] >> 16) == tag && (w[3] >> 16) == tag) break;
                __builtin_amdgcn_s_sleep(1);
            }
            uint32 p0 = (w[0] & 0xFFFFu) | (w[1] << 16);
            uint32 p1 = (w[2] & 0xFFFFu) | (w[3] << 16);
            r2[gb][2 * k4g]     = __builtin_bit_cast(half2_t, p0);
            r2[gb][2 * k4g + 1] = __builtin_bit_cast(half2_t, p1);
        }
        __syncthreads();   // B3 (r2 ready for next ph1)
    }

    // ---- epilogue: out[:, TT-1, :] from r2 = relu(h_TT) ----
    if (wv >= 4 && sl < OO) {
        int b = wv - 4;
        int k2 = lane * 4;
        float p = 0.f;
        p = fdot2f(r2[b][k2],     wo2[k2],     p);
        p = fdot2f(r2[b][k2 + 1], wo2[k2 + 1], p);
        p = fdot2f(r2[b][k2 + 2], wo2[k2 + 2], p);
        p = fdot2f(r2[b][k2 + 3], wo2[k2 + 3], p);
        #pragma unroll
        for (int d = 32; d >= 1; d >>= 1) p += __shfl_xor(p, d);
        if (lane == 0) out[((size_t)(cq * BT + b) * TT + (TT - 1)) * OO + sl] = p;
    }
}

// ---------------- host launcher ----------------
extern "C" void kernel_launch(void* const* d_in, const int* in_sizes, int n_in,
                              void* d_out, int out_size, void* d_ws, size_t ws_size,
                              hipStream_t stream) {
    const float* input     = (const float*)d_in[0];
    const float* noise     = (const float*)d_in[1];
    const float* wi        = (const float*)d_in[2];
    const float* si        = (const float*)d_in[3];
    const float* wrec      = (const float*)d_in[4];
    const float* bvec      = (const float*)d_in[5];
    const float* wo        = (const float*)d_in[6];
    const float* so        = (const float*)d_in[7];
    const float* wi_mask   = (const float*)d_in[8];
    const float* wrec_mask = (const float*)d_in[9];
    const float* wo_mask   = (const float*)d_in[10];
    const float* h0        = (const float*)d_in[11];

    float* out  = (float*)d_out;
    float* traj = out + (size_t)BB * TT * OO;
    uint32* ex  = (uint32*)d_ws;

    // clear exchange tags every call (stale-tag / first-call safety; replay-safe)
    (void)hipMemsetAsync(d_ws, 0, (size_t)NC * 2 * BT * HH * 4, stream);

    rnn_clique<<<dim3(NC * G_SLICES), dim3(512), 0, stream>>>(
        input, noise, wi, si, wrec, bvec, wo, so,
        wi_mask, wrec_mask, wo_mask, h0, ex, out, traj);
}

// Round 8
// 1688.974 us; speedup vs baseline: 5.8480x; 1.0671x over previous
//
#include <hip/hip_runtime.h>
#include <hip/hip_bf16.h>
#include <cstddef>
#include <cstdint>

#define BB 64
#define TT 1024
#define HH 512
#define II 64
#define OO 8
#define NOISE_STD 0.05f
#define ALPHA 0.2f

#define G_SLICES 16      // blocks (column slices) per clique
#define BT 4             // batches per clique
#define NC (BB/BT)       // 16 cliques
#define K4EXT 160
#define R2STRIDE 328     // r2 row stride in half2 slots

typedef _Float16 half2_t __attribute__((ext_vector_type(2)));
typedef unsigned int uint32;
typedef uint32 uint4_t __attribute__((ext_vector_type(4)));

#if __has_builtin(__builtin_amdgcn_fdot2)
__device__ __forceinline__ float fdot2f(half2_t a, half2_t b, float c) {
    return __builtin_amdgcn_fdot2(a, b, c, false);
}
#else
__device__ __forceinline__ float fdot2f(half2_t a, half2_t b, float c) {
    return c + (float)a[0] * (float)b[0] + (float)a[1] * (float)b[1];
}
#endif

__device__ __forceinline__ half2_t pkrtz(float a, float b) {
    return __builtin_bit_cast(half2_t, __builtin_amdgcn_cvt_pkrtz(a, b));
}

// 16B coherent load at L3 scope (bypasses non-coherent local L2) — cross-XCD safe
__device__ __forceinline__ uint4_t load4_sc1(const uint32* p) {
    uint4_t v;
    asm volatile("global_load_dwordx4 %0, %1, off sc1\n\t"
                 "s_waitcnt vmcnt(0)"
                 : "=v"(v) : "v"(p) : "memory");
    return v;
}
// 16B load at L2 scope (bypasses L1, reads the XCD-shared L2) — intra-XCD
__device__ __forceinline__ uint4_t load4_sc0(const uint32* p) {
    uint4_t v;
    asm volatile("global_load_dwordx4 %0, %1, off sc0\n\t"
                 "s_waitcnt vmcnt(0)"
                 : "=v"(v) : "v"(p) : "memory");
    return v;
}
// plain store: lands in the XCD-shared (write-back) L2 — intra-XCD publish
__device__ __forceinline__ void store1_plain(uint32* p, uint32 v) {
    asm volatile("global_store_dword %0, %1, off" :: "v"(p), "v"(v) : "memory");
}

__global__ __launch_bounds__(512, 2)
void rnn_clique(const float* __restrict__ input, const float* __restrict__ noise,
                const float* __restrict__ wi, const float* __restrict__ si,
                const float* __restrict__ wrec, const float* __restrict__ bvec,
                const float* __restrict__ wo, const float* __restrict__ so,
                const float* __restrict__ wi_mask, const float* __restrict__ wrec_mask,
                const float* __restrict__ wo_mask, const float* __restrict__ h0,
                uint32* __restrict__ ex, float* __restrict__ out,
                float* __restrict__ traj)
{
    const int tid  = threadIdx.x;
    // clique = bid mod 16 -> all 16 blocks of a clique share bid mod 8
    // -> same XCD under round-robin dispatch (verified at runtime below)
    const int cq   = blockIdx.x & 15;
    const int sl   = blockIdx.x >> 4;
    const int wv   = tid >> 6;
    const int lane = tid & 63;

    __shared__ half2_t w2[K4EXT * 64];       // [k4][c][j], 40 KB
    __shared__ half2_t r2[BT][R2STRIDE];     // extended activation pairs
    __shared__ float   part[BT][8][32];      // per-wave matvec partials
    __shared__ half2_t wo2[256];             // wo_eff column (sl<8)
    __shared__ int     mode_sh;              // 1 = XCD-local exchange OK

    uint32* aux = ex + (size_t)NC * 2 * BT * HH;   // handshake region

    // ---- post this block's XCD id (agent-visible) before the long staging ----
    if (tid == 0) {
        uint32 xcc;
        asm volatile("s_getreg_b32 %0, hwreg(HW_REG_XCC_ID)" : "=s"(xcc));
        xcc &= 0xFFu;
        __hip_atomic_store(aux + cq * 16 + sl, (1u << 16) | xcc,
                           __ATOMIC_RELAXED, __HIP_MEMORY_SCOPE_AGENT);
    }

    // ---------------- stage extended weight slice (one-time) ----------------
    {
        const int c = tid & 31, kg = tid >> 5;   // kg 0..15
        const int gc = sl * 32 + c;
        for (int m = 0; m < 10; ++m) {
            int k4 = m * 16 + kg;
            float v[4];
            #pragma unroll
            for (int q = 0; q < 4; ++q) {
                int kap = k4 * 4 + q;
                float x;
                if (kap < HH) {
                    x = fabsf(wrec[(size_t)kap * HH + gc]) * wrec_mask[(size_t)kap * HH + gc];
                } else if (kap < HH + II) {
                    int i = kap - HH;
                    x = wi[(size_t)i * HH + gc] * si[i] * wi_mask[(size_t)i * HH + gc];
                } else if (kap == HH + II) {
                    x = bvec[gc];
                } else {
                    x = 0.f;
                }
                v[q] = x;
            }
            w2[k4 * 64 + c * 2]     = pkrtz(v[0], v[1]);
            w2[k4 * 64 + c * 2 + 1] = pkrtz(v[2], v[3]);
        }
    }
    if (sl < OO && tid < 256) {      // wo column for this block's output index
        int k2 = tid, o = sl;
        float v0 = wo[(size_t)(2 * k2) * OO + o] * so[o] * wo_mask[(size_t)(2 * k2) * OO + o];
        float v1 = wo[(size_t)(2 * k2 + 1) * OO + o] * so[o] * wo_mask[(size_t)(2 * k2 + 1) * OO + o];
        wo2[k2] = pkrtz(v0, v1);
    }
    if (tid < 128) {                 // r2 slots 0..255 from relu(h0)
        int k4 = tid;
        float v0 = fmaxf(h0[4 * k4 + 0], 0.f), v1 = fmaxf(h0[4 * k4 + 1], 0.f);
        float v2 = fmaxf(h0[4 * k4 + 2], 0.f), v3 = fmaxf(h0[4 * k4 + 3], 0.f);
        half2_t p0 = pkrtz(v0, v1), p1 = pkrtz(v2, v3);
        for (int b = 0; b < BT; ++b) { r2[b][2 * k4] = p0; r2[b][2 * k4 + 1] = p1; }
    }
    if (tid < BT) {                  // const slot + zero pads
        r2[tid][288] = half2_t{(_Float16)1.f, (_Float16)0.f};
        for (int s = 289; s < R2STRIDE; ++s) r2[tid][s] = half2_t{(_Float16)0.f, (_Float16)0.f};
    }
    if (wv >= 4 && lane < 32) {      // x[t=0] slots 256..287
        int b = wv - 4, i2 = lane;
        const float* xp = input + ((size_t)(cq * BT + b) * TT + 0) * II + 2 * i2;
        r2[b][256 + i2] = pkrtz(xp[0], xp[1]);
    }

    // persistent per-lane state for finalize lanes (waves 0..3, lanes 0..31)
    float h_st = 0.f, n_reg = 0.f;
    float* trajp = nullptr;
    const float* noisep = nullptr;
    uint32* exw = nullptr;   // writer's word slot base (parity 0)
    if (wv < BT && lane < 32) {
        int b = wv, c = lane, gc = sl * 32 + c, bg = cq * BT + b;
        h_st   = h0[gc];
        noisep = noise + (size_t)bg * TT * HH;
        trajp  = traj + (size_t)bg * (TT + 1) * HH;
        n_reg  = noisep[gc];            // noise[b][0][gc]
        trajp[gc] = h_st;               // trajectories[:,0,:] (plain store)
        exw = ex + (size_t)((cq * 2 + 0) * BT + b) * HH + gc;
    }

    // ---- collect the clique's XCD ids; uniform -> L2-local fast path ----
    if (wv == 0) {
        uint32 v = (1u << 16);
        for (;;) {
            if (lane < 16)
                v = __hip_atomic_load(aux + cq * 16 + lane,
                                      __ATOMIC_RELAXED, __HIP_MEMORY_SCOPE_AGENT);
            if (__ballot((v >> 16) == 1u) == ~0ull) break;
            __builtin_amdgcn_s_sleep(1);
        }
        uint32 myx = v & 0xFFFFu;
        uint32 x0  = __shfl(myx, 0);
        bool eq = (lane < 16) ? (myx == x0) : true;
        if (lane == 0) mode_sh = (__ballot(eq) == ~0ull) ? 1 : 0;
    }
    __syncthreads();
    const bool local_mode = (mode_sh != 0);

    const int c_    = lane & 31;
    const int shalf = lane >> 5;
    const int seg   = wv * 2 + shalf;          // 0..15, k2 range [seg*20, seg*20+20)

    // gather mapping: thread covers 4 consecutive columns (one dwordx4)
    const int gb  = tid >> 7;          // batch 0..3
    const int k4g = tid & 127;         // column group
    uint32* exg0 = ex + (size_t)((cq * 2 + 0) * BT + gb) * HH + (size_t)(4 * k4g);
    const size_t expar = (size_t)BT * HH;   // parity stride in uints

    for (int t = 0; t < TT; ++t) {
        // ---- ph1: matvec over extended K (wrec + wi + bias folded) ----
        float acc0 = 0.f, acc1 = 0.f, acc2 = 0.f, acc3 = 0.f;
        #pragma unroll
        for (int ch = 0; ch < 5; ++ch) {
            int k2b = seg * 20 + ch * 4;
            int k4b = seg * 10 + ch * 2;
            half2_t w00 = w2[k4b * 64 + c_ * 2];
            half2_t w01 = w2[k4b * 64 + c_ * 2 + 1];
            half2_t w10 = w2[(k4b + 1) * 64 + c_ * 2];
            half2_t w11 = w2[(k4b + 1) * 64 + c_ * 2 + 1];
            {
                half2_t ra = r2[0][k2b], rb = r2[0][k2b + 1], rc = r2[0][k2b + 2], rd = r2[0][k2b + 3];
                acc0 = fdot2f(ra, w00, acc0); acc0 = fdot2f(rb, w01, acc0);
                acc0 = fdot2f(rc, w10, acc0); acc0 = fdot2f(rd, w11, acc0);
            }
            {
                half2_t ra = r2[1][k2b], rb = r2[1][k2b + 1], rc = r2[1][k2b + 2], rd = r2[1][k2b + 3];
                acc1 = fdot2f(ra, w00, acc1); acc1 = fdot2f(rb, w01, acc1);
                acc1 = fdot2f(rc, w10, acc1); acc1 = fdot2f(rd, w11, acc1);
            }
            {
                half2_t ra = r2[2][k2b], rb = r2[2][k2b + 1], rc = r2[2][k2b + 2], rd = r2[2][k2b + 3];
                acc2 = fdot2f(ra, w00, acc2); acc2 = fdot2f(rb, w01, acc2);
                acc2 = fdot2f(rc, w10, acc2); acc2 = fdot2f(rd, w11, acc2);
            }
            {
                half2_t ra = r2[3][k2b], rb = r2[3][k2b + 1], rc = r2[3][k2b + 2], rd = r2[3][k2b + 3];
                acc3 = fdot2f(ra, w00, acc3); acc3 = fdot2f(rb, w01, acc3);
                acc3 = fdot2f(rc, w10, acc3); acc3 = fdot2f(rd, w11, acc3);
            }
        }
        acc0 += __shfl_xor(acc0, 32);
        acc1 += __shfl_xor(acc1, 32);
        acc2 += __shfl_xor(acc2, 32);
        acc3 += __shfl_xor(acc3, 32);
        if (shalf == 0) {
            part[0][wv][c_] = acc0;
            part[1][wv][c_] = acc1;
            part[2][wv][c_] = acc2;
            part[3][wv][c_] = acc3;
        }
        __syncthreads();   // B1

        const uint32 tag = (uint32)(t + 1);
        const size_t poff = (size_t)((t + 1) & 1) * expar;

        // ---- ph3: finalize+publish (waves 0-3) | out-proj + x-stage (waves 4-7) ----
        if (wv < BT && lane < 32) {
            int b = wv, c = lane, gc = sl * 32 + c;
            float mv = 0.f;
            #pragma unroll
            for (int m = 0; m < 8; ++m) mv += part[b][m][c];
            float hn = (1.f - ALPHA) * h_st + ALPHA * mv + NOISE_STD * n_reg;
            h_st = hn;
            // pack f16(relu(h)) | tag<<16 into ONE dword: single-copy atomic
            uint32 r16 = __builtin_bit_cast(uint32,
                           __builtin_amdgcn_cvt_pkrtz(fmaxf(hn, 0.f), 0.f)) & 0xFFFFu;
            uint32 word = (tag << 16) | r16;
            if (local_mode) {
                store1_plain(exw + poff, word);      // lands in XCD-shared L2
            } else {
                __hip_atomic_store(exw + poff, word,
                                   __ATOMIC_RELAXED, __HIP_MEMORY_SCOPE_AGENT);
            }
            trajp[(size_t)(t + 1) * HH + gc] = hn;                // plain output store
            int tn = (t + 1 < TT) ? (t + 1) : (TT - 1);
            n_reg = noisep[(size_t)tn * HH + gc];
        } else if (wv >= 4) {
            if (sl < OO && t > 0) {
                int b = wv - 4;
                int k2 = lane * 4;
                float p = 0.f;
                p = fdot2f(r2[b][k2],     wo2[k2],     p);
                p = fdot2f(r2[b][k2 + 1], wo2[k2 + 1], p);
                p = fdot2f(r2[b][k2 + 2], wo2[k2 + 2], p);
                p = fdot2f(r2[b][k2 + 3], wo2[k2 + 3], p);
                #pragma unroll
                for (int d = 32; d >= 1; d >>= 1) p += __shfl_xor(p, d);
                if (lane == 0) out[((size_t)(cq * BT + b) * TT + (t - 1)) * OO + sl] = p;
            }
            if (lane < 32) {          // stage x[t+1] into slots 256..287
                int b = wv - 4, i2 = lane;
                int tn = (t + 1 < TT) ? (t + 1) : (TT - 1);
                const float* xp = input + ((size_t)(cq * BT + b) * TT + tn) * II + 2 * i2;
                r2[b][256 + i2] = pkrtz(xp[0], xp[1]);
            }
        }
        __syncthreads();   // B2 (out-proj done reading r2 before gather overwrites)

        // ---- ph7: tagged gather of relu(h_{t+1}) (poll the data itself) ----
        {
            const uint32* g0 = exg0 + poff;
            uint4_t w;
            if (local_mode) {
                for (;;) {
                    w = load4_sc0(g0);
                    if ((w[0] >> 16) == tag && (w[1] >> 16) == tag &&
                        (w[2] >> 16) == tag && (w[3] >> 16) == tag) break;
                    __builtin_amdgcn_s_sleep(1);
                }
            } else {
                for (;;) {
                    w = load4_sc1(g0);
                    if ((w[0] >> 16) == tag && (w[1] >> 16) == tag &&
                        (w[2] >> 16) == tag && (w[3] >> 16) == tag) break;
                    __builtin_amdgcn_s_sleep(1);
                }
            }
            uint32 p0 = (w[0] & 0xFFFFu) | (w[1] << 16);
            uint32 p1 = (w[2] & 0xFFFFu) | (w[3] << 16);
            r2[gb][2 * k4g]     = __builtin_bit_cast(half2_t, p0);
            r2[gb][2 * k4g + 1] = __builtin_bit_cast(half2_t, p1);
        }
        __syncthreads();   // B3 (r2 ready for next ph1)
    }

    // ---- epilogue: out[:, TT-1, :] from r2 = relu(h_TT) ----
    if (wv >= 4 && sl < OO) {
        int b = wv - 4;
        int k2 = lane * 4;
        float p = 0.f;
        p = fdot2f(r2[b][k2],     wo2[k2],     p);
        p = fdot2f(r2[b][k2 + 1], wo2[k2 + 1], p);
        p = fdot2f(r2[b][k2 + 2], wo2[k2 + 2], p);
        p = fdot2f(r2[b][k2 + 3], wo2[k2 + 3], p);
        #pragma unroll
        for (int d = 32; d >= 1; d >>= 1) p += __shfl_xor(p, d);
        if (lane == 0) out[((size_t)(cq * BT + b) * TT + (TT - 1)) * OO + sl] = p;
    }
}

// ---------------- host launcher ----------------
extern "C" void kernel_launch(void* const* d_in, const int* in_sizes, int n_in,
                              void* d_out, int out_size, void* d_ws, size_t ws_size,
                              hipStream_t stream) {
    const float* input     = (const float*)d_in[0];
    const float* noise     = (const float*)d_in[1];
    const float* wi        = (const float*)d_in[2];
    const float* si        = (const float*)d_in[3];
    const float* wrec      = (const float*)d_in[4];
    const float* bvec      = (const float*)d_in[5];
    const float* wo        = (const float*)d_in[6];
    const float* so        = (const float*)d_in[7];
    const float* wi_mask   = (const float*)d_in[8];
    const float* wrec_mask = (const float*)d_in[9];
    const float* wo_mask   = (const float*)d_in[10];
    const float* h0        = (const float*)d_in[11];

    float* out  = (float*)d_out;
    float* traj = out + (size_t)BB * TT * OO;
    uint32* ex  = (uint32*)d_ws;

    // clear exchange + handshake tags every call (replay-safe)
    (void)hipMemsetAsync(d_ws, 0,
        (size_t)(NC * 2 * BT * HH + NC * G_SLICES) * sizeof(uint32), stream);

    rnn_clique<<<dim3(NC * G_SLICES), dim3(512), 0, stream>>>(
        input, noise, wi, si, wrec, bvec, wo, so,
        wi_mask, wrec_mask, wo_mask, h0, ex, out, traj);
}

// Round 9
// 1608.138 us; speedup vs baseline: 6.1420x; 1.0503x over previous
//
#include <hip/hip_runtime.h>
#include <hip/hip_bf16.h>
#include <cstddef>
#include <cstdint>

#define BB 64
#define TT 1024
#define HH 512
#define II 64
#define OO 8
#define NOISE_STD 0.05f
#define ALPHA 0.2f

#define G_SLICES 16      // blocks (column slices) per clique
#define BT 4             // batches per clique
#define NC (BB/BT)       // 16 cliques
#define K4EXT 160
#define R2STRIDE 328     // r2 row stride in half2 slots

typedef _Float16 half2_t __attribute__((ext_vector_type(2)));
typedef unsigned int uint32;
typedef uint32 uint4_t __attribute__((ext_vector_type(4)));

#if __has_builtin(__builtin_amdgcn_fdot2)
__device__ __forceinline__ float fdot2f(half2_t a, half2_t b, float c) {
    return __builtin_amdgcn_fdot2(a, b, c, false);
}
#else
__device__ __forceinline__ float fdot2f(half2_t a, half2_t b, float c) {
    return c + (float)a[0] * (float)b[0] + (float)a[1] * (float)b[1];
}
#endif

__device__ __forceinline__ half2_t pkrtz(float a, float b) {
    return __builtin_bit_cast(half2_t, __builtin_amdgcn_cvt_pkrtz(a, b));
}

// 16B coherent load at L3 scope (bypasses non-coherent local L2) — cross-XCD safe
__device__ __forceinline__ uint4_t load4_sc1(const uint32* p) {
    uint4_t v;
    asm volatile("global_load_dwordx4 %0, %1, off sc1\n\t"
                 "s_waitcnt vmcnt(0)"
                 : "=v"(v) : "v"(p) : "memory");
    return v;
}
// 16B load at L2 scope (bypasses L1, reads the XCD-shared L2) — intra-XCD
__device__ __forceinline__ uint4_t load4_sc0(const uint32* p) {
    uint4_t v;
    asm volatile("global_load_dwordx4 %0, %1, off sc0\n\t"
                 "s_waitcnt vmcnt(0)"
                 : "=v"(v) : "v"(p) : "memory");
    return v;
}
// plain store: lands in the XCD-shared (write-back) L2 — intra-XCD publish
__device__ __forceinline__ void store1_plain(uint32* p, uint32 v) {
    asm volatile("global_store_dword %0, %1, off" :: "v"(p), "v"(v) : "memory");
}

__global__ __launch_bounds__(512, 2)
void rnn_clique(const float* __restrict__ input, const float* __restrict__ noise,
                const float* __restrict__ wi, const float* __restrict__ si,
                const float* __restrict__ wrec, const float* __restrict__ bvec,
                const float* __restrict__ wo, const float* __restrict__ so,
                const float* __restrict__ wi_mask, const float* __restrict__ wrec_mask,
                const float* __restrict__ wo_mask, const float* __restrict__ h0,
                uint32* __restrict__ ex, float* __restrict__ out,
                float* __restrict__ traj)
{
    const int tid  = threadIdx.x;
    // clique = bid mod 16 -> all 16 blocks of a clique share bid mod 8
    // -> same XCD under round-robin dispatch (verified at runtime)
    const int cq   = blockIdx.x & 15;
    const int sl   = blockIdx.x >> 4;
    const int wv   = tid >> 6;
    const int lane = tid & 63;

    __shared__ half2_t w2[K4EXT * 64];       // staging for eff-weights, 40 KB
    __shared__ half2_t r2[2][BT][R2STRIDE];  // parity-double-buffered activations
    __shared__ float   part[BT][8][32];      // per-wave matvec partials
    __shared__ half2_t wo2[256];             // wo_eff column (sl<8)
    __shared__ int     mode_sh;              // 1 = XCD-local exchange OK

    uint32* aux = ex + (size_t)NC * 2 * BT * HH;   // handshake region

    if (tid == 0) {
        uint32 xcc;
        asm volatile("s_getreg_b32 %0, hwreg(HW_REG_XCC_ID)" : "=s"(xcc));
        xcc &= 0xFFu;
        __hip_atomic_store(aux + cq * 16 + sl, (1u << 16) | xcc,
                           __ATOMIC_RELAXED, __HIP_MEMORY_SCOPE_AGENT);
    }

    // ---------------- stage extended weight slice ----------------
    {
        const int c = tid & 31, kg = tid >> 5;
        const int gc = sl * 32 + c;
        for (int m = 0; m < 10; ++m) {
            int k4 = m * 16 + kg;
            float v[4];
            #pragma unroll
            for (int q = 0; q < 4; ++q) {
                int kap = k4 * 4 + q;
                float x;
                if (kap < HH) {
                    x = fabsf(wrec[(size_t)kap * HH + gc]) * wrec_mask[(size_t)kap * HH + gc];
                } else if (kap < HH + II) {
                    int i = kap - HH;
                    x = wi[(size_t)i * HH + gc] * si[i] * wi_mask[(size_t)i * HH + gc];
                } else if (kap == HH + II) {
                    x = bvec[gc];
                } else {
                    x = 0.f;
                }
                v[q] = x;
            }
            w2[k4 * 64 + c * 2]     = pkrtz(v[0], v[1]);
            w2[k4 * 64 + c * 2 + 1] = pkrtz(v[2], v[3]);
        }
    }
    if (sl < OO && tid < 256) {
        int k2 = tid, o = sl;
        float v0 = wo[(size_t)(2 * k2) * OO + o] * so[o] * wo_mask[(size_t)(2 * k2) * OO + o];
        float v1 = wo[(size_t)(2 * k2 + 1) * OO + o] * so[o] * wo_mask[(size_t)(2 * k2 + 1) * OO + o];
        wo2[k2] = pkrtz(v0, v1);
    }
    if (tid < 128) {                 // r2[0] h-slots from relu(h0)
        int k4 = tid;
        float v0 = fmaxf(h0[4 * k4 + 0], 0.f), v1 = fmaxf(h0[4 * k4 + 1], 0.f);
        float v2 = fmaxf(h0[4 * k4 + 2], 0.f), v3 = fmaxf(h0[4 * k4 + 3], 0.f);
        half2_t p0 = pkrtz(v0, v1), p1 = pkrtz(v2, v3);
        for (int b = 0; b < BT; ++b) { r2[0][b][2 * k4] = p0; r2[0][b][2 * k4 + 1] = p1; }
    }
    if (tid < 8) {                   // bias + pads in BOTH parity buffers
        int par = tid & 1, b = tid >> 1;
        r2[par][b][288] = half2_t{(_Float16)1.f, (_Float16)0.f};
        for (int s = 289; s < R2STRIDE; ++s) r2[par][b][s] = half2_t{(_Float16)0.f, (_Float16)0.f};
    }
    if (wv >= 4 && lane < 32) {      // x(0) into r2[0]
        int b = wv - 4, i2 = lane;
        const float* xp = input + ((size_t)(cq * BT + b) * TT + 0) * II + 2 * i2;
        r2[0][b][256 + i2] = pkrtz(xp[0], xp[1]);
    }

    // persistent per-lane state for finalize lanes
    float h_st = 0.f, n_reg = 0.f, n_reg2 = 0.f;
    float* trajp = nullptr;
    const float* noisep = nullptr;
    uint32* exw = nullptr;
    if (wv < BT && lane < 32) {
        int b = wv, c = lane, gc = sl * 32 + c, bg = cq * BT + b;
        h_st   = h0[gc];
        noisep = noise + (size_t)bg * TT * HH;
        trajp  = traj + (size_t)bg * (TT + 1) * HH;
        n_reg  = noisep[gc];                 // noise[b][0][gc]
        n_reg2 = noisep[(size_t)HH + gc];    // noise[b][1][gc]
        trajp[gc] = h_st;
        exw = ex + (size_t)((cq * 2 + 0) * BT + b) * HH + gc;
    }
    __syncthreads();

    const int c_    = lane & 31;
    const int shalf = lane >> 5;
    const int seg   = wv * 2 + shalf;          // 0..15

    // ---- hoist this thread's weights into registers (20 half2) ----
    half2_t wr[5][4];
    #pragma unroll
    for (int ch = 0; ch < 5; ++ch) {
        int k4b = seg * 10 + ch * 2;
        wr[ch][0] = w2[k4b * 64 + c_ * 2];
        wr[ch][1] = w2[k4b * 64 + c_ * 2 + 1];
        wr[ch][2] = w2[(k4b + 1) * 64 + c_ * 2];
        wr[ch][3] = w2[(k4b + 1) * 64 + c_ * 2 + 1];
    }

    // ---- collect the clique's XCD ids; uniform -> L2-local fast path ----
    if (wv == 0) {
        uint32 v = (1u << 16);
        for (;;) {
            if (lane < 16)
                v = __hip_atomic_load(aux + cq * 16 + lane,
                                      __ATOMIC_RELAXED, __HIP_MEMORY_SCOPE_AGENT);
            if (__ballot((v >> 16) == 1u) == ~0ull) break;
            __builtin_amdgcn_s_sleep(1);
        }
        uint32 myx = v & 0xFFFFu;
        uint32 x0  = __shfl(myx, 0);
        bool eq = (lane < 16) ? (myx == x0) : true;
        if (lane == 0) mode_sh = (__ballot(eq) == ~0ull) ? 1 : 0;
    }
    __syncthreads();
    const bool local_mode = (mode_sh != 0);

    // gather mapping: thread covers 4 consecutive columns (one dwordx4)
    const int gb  = tid >> 7;
    const int k4g = tid & 127;
    uint32* exg0 = ex + (size_t)((cq * 2 + 0) * BT + gb) * HH + (size_t)(4 * k4g);
    const size_t expar = (size_t)BT * HH;

    for (int t = 0; t < TT; ++t) {
        const int p = t & 1;

        // ---- matvec from r2[p] with register weights ----
        float acc0 = 0.f, acc1 = 0.f, acc2 = 0.f, acc3 = 0.f;
        #pragma unroll
        for (int ch = 0; ch < 5; ++ch) {
            int k2b = seg * 20 + ch * 4;
            {
                half2_t ra = r2[p][0][k2b], rb = r2[p][0][k2b + 1], rc = r2[p][0][k2b + 2], rd = r2[p][0][k2b + 3];
                acc0 = fdot2f(ra, wr[ch][0], acc0); acc0 = fdot2f(rb, wr[ch][1], acc0);
                acc0 = fdot2f(rc, wr[ch][2], acc0); acc0 = fdot2f(rd, wr[ch][3], acc0);
            }
            {
                half2_t ra = r2[p][1][k2b], rb = r2[p][1][k2b + 1], rc = r2[p][1][k2b + 2], rd = r2[p][1][k2b + 3];
                acc1 = fdot2f(ra, wr[ch][0], acc1); acc1 = fdot2f(rb, wr[ch][1], acc1);
                acc1 = fdot2f(rc, wr[ch][2], acc1); acc1 = fdot2f(rd, wr[ch][3], acc1);
            }
            {
                half2_t ra = r2[p][2][k2b], rb = r2[p][2][k2b + 1], rc = r2[p][2][k2b + 2], rd = r2[p][2][k2b + 3];
                acc2 = fdot2f(ra, wr[ch][0], acc2); acc2 = fdot2f(rb, wr[ch][1], acc2);
                acc2 = fdot2f(rc, wr[ch][2], acc2); acc2 = fdot2f(rd, wr[ch][3], acc2);
            }
            {
                half2_t ra = r2[p][3][k2b], rb = r2[p][3][k2b + 1], rc = r2[p][3][k2b + 2], rd = r2[p][3][k2b + 3];
                acc3 = fdot2f(ra, wr[ch][0], acc3); acc3 = fdot2f(rb, wr[ch][1], acc3);
                acc3 = fdot2f(rc, wr[ch][2], acc3); acc3 = fdot2f(rd, wr[ch][3], acc3);
            }
        }
        acc0 += __shfl_xor(acc0, 32);
        acc1 += __shfl_xor(acc1, 32);
        acc2 += __shfl_xor(acc2, 32);
        acc3 += __shfl_xor(acc3, 32);
        if (shalf == 0) {
            part[0][wv][c_] = acc0;
            part[1][wv][c_] = acc1;
            part[2][wv][c_] = acc2;
            part[3][wv][c_] = acc3;
        }
        __syncthreads();   // B1

        const uint32 tag = (uint32)(t + 2);      // tag for h(t+1); memset-0 never matches
        const size_t poff = (size_t)p * expar;   // h(t+1) lives at parity t&1

        if (wv < BT && lane < 32) {
            // ---- finalize + publish ----
            int b = wv, c = lane, gc = sl * 32 + c;
            float mv = 0.f;
            #pragma unroll
            for (int m = 0; m < 8; ++m) mv += part[b][m][c];
            float hn = (1.f - ALPHA) * h_st + ALPHA * mv + NOISE_STD * n_reg;
            h_st = hn;
            uint32 r16 = __builtin_bit_cast(uint32,
                           __builtin_amdgcn_cvt_pkrtz(fmaxf(hn, 0.f), 0.f)) & 0xFFFFu;
            uint32 word = (tag << 16) | r16;
            if (local_mode) {
                store1_plain(exw + poff, word);
            } else {
                __hip_atomic_store(exw + poff, word,
                                   __ATOMIC_RELAXED, __HIP_MEMORY_SCOPE_AGENT);
            }
            trajp[(size_t)(t + 1) * HH + gc] = hn;
            n_reg = n_reg2;
            int tn = (t + 2 < TT) ? (t + 2) : (TT - 1);
            n_reg2 = noisep[(size_t)tn * HH + gc];
        } else if (wv >= 4) {
            if (sl < OO && t > 0) {
                // out(t-1) = relu(h(t)) . wo  from r2[p]
                int b = wv - 4;
                int k2 = lane * 4;
                float q = 0.f;
                q = fdot2f(r2[p][b][k2],     wo2[k2],     q);
                q = fdot2f(r2[p][b][k2 + 1], wo2[k2 + 1], q);
                q = fdot2f(r2[p][b][k2 + 2], wo2[k2 + 2], q);
                q = fdot2f(r2[p][b][k2 + 3], wo2[k2 + 3], q);
                #pragma unroll
                for (int d = 32; d >= 1; d >>= 1) q += __shfl_xor(q, d);
                if (lane == 0) out[((size_t)(cq * BT + b) * TT + (t - 1)) * OO + sl] = q;
            }
            if (lane < 32) {          // stage x(t+1) into r2[p^1]
                int b = wv - 4, i2 = lane;
                int tn = (t + 1 < TT) ? (t + 1) : (TT - 1);
                const float* xp = input + ((size_t)(cq * BT + b) * TT + tn) * II + 2 * i2;
                r2[p ^ 1][b][256 + i2] = pkrtz(xp[0], xp[1]);
            }
        }

        // ---- gather h(t+1) -> r2[p^1] (all threads; overlaps with above) ----
        {
            const uint32* g0 = exg0 + poff;
            uint4_t w;
            int spins = 0;
            if (local_mode) {
                for (;;) {
                    w = load4_sc0(g0);
                    if ((w[0] >> 16) == tag && (w[1] >> 16) == tag &&
                        (w[2] >> 16) == tag && (w[3] >> 16) == tag) break;
                    if (++spins > 8) __builtin_amdgcn_s_sleep(1);
                }
            } else {
                for (;;) {
                    w = load4_sc1(g0);
                    if ((w[0] >> 16) == tag && (w[1] >> 16) == tag &&
                        (w[2] >> 16) == tag && (w[3] >> 16) == tag) break;
                    __builtin_amdgcn_s_sleep(1);
                }
            }
            uint32 q0 = (w[0] & 0xFFFFu) | (w[1] << 16);
            uint32 q1 = (w[2] & 0xFFFFu) | (w[3] << 16);
            r2[p ^ 1][gb][2 * k4g]     = __builtin_bit_cast(half2_t, q0);
            r2[p ^ 1][gb][2 * k4g + 1] = __builtin_bit_cast(half2_t, q1);
        }
        __syncthreads();   // B2 (r2[p^1] ready; part[] consumed)
    }

    // ---- epilogue: out(TT-1) from r2[0] = relu(h(TT)) ----
    if (wv >= 4 && sl < OO) {
        int b = wv - 4;
        int k2 = lane * 4;
        float q = 0.f;
        q = fdot2f(r2[0][b][k2],     wo2[k2],     q);
        q = fdot2f(r2[0][b][k2 + 1], wo2[k2 + 1], q);
        q = fdot2f(r2[0][b][k2 + 2], wo2[k2 + 2], q);
        q = fdot2f(r2[0][b][k2 + 3], wo2[k2 + 3], q);
        #pragma unroll
        for (int d = 32; d >= 1; d >>= 1) q += __shfl_xor(q, d);
        if (lane == 0) out[((size_t)(cq * BT + b) * TT + (TT - 1)) * OO + sl] = q;
    }
}

// ---------------- host launcher ----------------
extern "C" void kernel_launch(void* const* d_in, const int* in_sizes, int n_in,
                              void* d_out, int out_size, void* d_ws, size_t ws_size,
                              hipStream_t stream) {
    const float* input     = (const float*)d_in[0];
    const float* noise     = (const float*)d_in[1];
    const float* wi        = (const float*)d_in[2];
    const float* si        = (const float*)d_in[3];
    const float* wrec      = (const float*)d_in[4];
    const float* bvec      = (const float*)d_in[5];
    const float* wo        = (const float*)d_in[6];
    const float* so        = (const float*)d_in[7];
    const float* wi_mask   = (const float*)d_in[8];
    const float* wrec_mask = (const float*)d_in[9];
    const float* wo_mask   = (const float*)d_in[10];
    const float* h0        = (const float*)d_in[11];

    float* out  = (float*)d_out;
    float* traj = out + (size_t)BB * TT * OO;
    uint32* ex  = (uint32*)d_ws;

    // clear exchange + handshake tags every call (replay-safe)
    (void)hipMemsetAsync(d_ws, 0,
        (size_t)(NC * 2 * BT * HH + NC * G_SLICES) * sizeof(uint32), stream);

    rnn_clique<<<dim3(NC * G_SLICES), dim3(512), 0, stream>>>(
        input, noise, wi, si, wrec, bvec, wo, so,
        wi_mask, wrec_mask, wo_mask, h0, ex, out, traj);
}